// Round 1
// baseline (73.206 us; speedup 1.0000x reference)
//
#include <hip/hip_runtime.h>

#define NQ 16

// mag * (-i)^k
__device__ __forceinline__ float2 phase_val(float mag, int k) {
    switch (k & 3) {
        case 0:  return make_float2(mag, 0.f);
        case 1:  return make_float2(0.f, -mag);
        case 2:  return make_float2(-mag, 0.f);
        default: return make_float2(0.f, mag);
    }
}

// One block per sample. 256 threads.
//
// Math: state = C2 R2 C1 R1 |0>, R1 = RX(z+params+w0) per wire (RX angles add),
// ring CNOTs are basis permutations (C psi)[y] = psi[g(y)],
//   g0 = y0^y15, g1 = y1^y0^y15, gq = y_{q-1}^y_q (q>=2)   [verified on n=2]
// Measurement backprop through C2: <Z_i> = sum_u (-1)^{F_i(u)} |phi[u]|^2 with
//   F_0 = parity(u1..u15), F_i = parity(u0..ui), phi = R2 C1 chi.
// C1 chi factors rank-4 across the hi(0..7)/lo(8..15) cut (coupling only via
// bits y7,y15):  C1chi = sum_{a,b} x_ab (x) y_ab.
extern "C" __global__ __launch_bounds__(256)
void qsim_kernel(const float* __restrict__ z,
                 const float* __restrict__ params,
                 const float* __restrict__ ew,
                 float* __restrict__ out)
{
    const int b   = blockIdx.x;
    const int tid = threadIdx.x;

    __shared__ float c1[NQ], s1[NQ], cw[NQ], sw[NQ];
    __shared__ float2 V[8][256];     // V[0..3] = X_p (hi sectors), V[4..7] = Y_p (lo sectors), p = 2a+b
    __shared__ float2 G[2][9][10];   // [side][mask][pair]

    if (tid < NQ) {
        float phi = z[b * NQ + tid] + params[tid] + ew[tid];   // embedding + layer0 RX merged
        c1[tid] = cosf(0.5f * phi);
        s1[tid] = sinf(0.5f * phi);
        float w = 0.5f * ew[NQ + tid];                          // layer1 RX
        cw[tid] = cosf(w);
        sw[tid] = sinf(w);
    }
    __syncthreads();

    // ---- Step 2: build the 8 sector vectors (C1 chi in rank-4 form) ----
    {
        const int h = tid;           // serves as both hi index (y0..y7) and lo index (y8..y15)
        int y[8];
#pragma unroll
        for (int q = 0; q < 8; ++q) y[q] = (h >> (7 - q)) & 1;

        // hi half: A[h, t=y15]
        float2 A[2];
#pragma unroll
        for (int t = 0; t < 2; ++t) {
            float mag = 1.f; int k = 0;
            int e = y[0] ^ t;          mag *= e ? s1[0] : c1[0]; k += e;
            e = y[1] ^ y[0] ^ t;       mag *= e ? s1[1] : c1[1]; k += e;
#pragma unroll
            for (int q = 2; q < 8; ++q) { e = y[q - 1] ^ y[q]; mag *= e ? s1[q] : c1[q]; k += e; }
            A[t] = phase_val(mag, k);
        }
        const int a_act = h & 1;     // y7
        V[2 * a_act + 0][h] = A[0];
        V[2 * a_act + 1][h] = A[1];
        V[2 * (1 - a_act) + 0][h] = make_float2(0.f, 0.f);
        V[2 * (1 - a_act) + 1][h] = make_float2(0.f, 0.f);

        // lo half: B[l, a=y7]  (y[j] here is bit y_{8+j})
        float2 Bv[2];
#pragma unroll
        for (int a = 0; a < 2; ++a) {
            float mag = 1.f; int k = 0;
            int e = a ^ y[0];          mag *= e ? s1[8] : c1[8]; k += e;
#pragma unroll
            for (int q = 9; q < 16; ++q) { e = y[q - 9] ^ y[q - 8]; mag *= e ? s1[q] : c1[q]; k += e; }
            Bv[a] = phase_val(mag, k);
        }
        const int b_act = h & 1;     // y15
        V[4 + 0 + b_act][h] = Bv[0];
        V[4 + 2 + b_act][h] = Bv[1];
        V[4 + 0 + (1 - b_act)][h] = make_float2(0.f, 0.f);
        V[4 + 2 + (1 - b_act)][h] = make_float2(0.f, 0.f);
    }
    __syncthreads();

    // ---- Step 3: apply R2 (layer-1 RX) to all 8 sector vectors ----
    // pass j: hi vectors get wire j, lo vectors get wire 8+j; both act on bit (7-j)
    for (int j = 0; j < 8; ++j) {
        const int bit = 7 - j;
#pragma unroll
        for (int r = 0; r < 4; ++r) {
            int task = tid + 256 * r;             // 0..1023 = 8 vecs * 128 pairs
            int vec  = task >> 7;
            int pr   = task & 127;
            int h0 = ((pr >> bit) << (bit + 1)) | (pr & ((1 << bit) - 1));
            int h1 = h0 | (1 << bit);
            int wire = (vec < 4) ? j : (8 + j);
            float c = cw[wire], s = sw[wire];
            float2 v0 = V[vec][h0], v1 = V[vec][h1];
            // [[c, -is],[-is, c]]
            float2 n0 = make_float2(c * v0.x + s * v1.y, c * v0.y - s * v1.x);
            float2 n1 = make_float2(s * v0.y + c * v1.x, -s * v0.x + c * v1.y);
            V[vec][h0] = n0;
            V[vec][h1] = n1;
        }
        __syncthreads();
    }

    // ---- Step 4: signed Gram sums  G[side][mask][pair] ----
    // pairs (p<=p'): (0,0)(0,1)(0,2)(0,3)(1,1)(1,2)(1,3)(2,2)(2,3)(3,3)
    if (tid < 180) {
        int side = tid / 90;                 // 0 = hi, 1 = lo
        int rest = tid - side * 90;
        int pp   = rest / 9;
        int m    = rest - pp * 9;
        int p, q2;
        if (pp < 4)      { p = 0; q2 = pp; }
        else if (pp < 7) { p = 1; q2 = pp - 3; }
        else if (pp < 9) { p = 2; q2 = pp - 5; }
        else             { p = 3; q2 = 3; }
        int mask;
        if (side == 0) mask = (m < 8) ? (((1 << (m + 1)) - 1) << (7 - m)) : 0x7F;  // {0..m}, m=8 -> {1..7}
        else           mask = (m == 0) ? 0 : (((1 << m) - 1) << (8 - m));          // {} or {8..m+7}
        const float2* Vp = V[p  + 4 * side];
        const float2* Vq = V[q2 + 4 * side];
        float ar = 0.f, ai = 0.f;
        for (int e2 = 0; e2 < 256; ++e2) {
            float2 u = Vp[e2], w = Vq[e2];
            float re = u.x * w.x + u.y * w.y;   // u * conj(w)
            float im = u.y * w.x - u.x * w.y;
            float sgn = (__popc(mask & e2) & 1) ? -1.f : 1.f;
            ar = fmaf(sgn, re, ar);
            ai = fmaf(sgn, im, ai);
        }
        G[side][m][pp] = make_float2(ar, ai);
    }
    __syncthreads();

    // ---- Step 5: combine  out[i] = sum_{p,p'} Gh_i(p,p') Gl_i(p,p') ----
    if (tid < NQ) {
        const int i = tid;
        int hm, lm;
        if (i == 0)      { hm = 8; lm = 8; }     // Z-string {1..15}
        else if (i <= 7) { hm = i; lm = 0; }     // {0..i}
        else             { hm = 7; lm = i - 7; } // {0..i}
        float r = 0.f;
#pragma unroll
        for (int pp = 0; pp < 10; ++pp) {
            float2 gh = G[0][hm][pp];
            float2 gl = G[1][lm][pp];
            float re = gh.x * gl.x - gh.y * gl.y;
            bool diag = (pp == 0) || (pp == 4) || (pp == 7) || (pp == 9);
            r += (diag ? 1.f : 2.f) * re;        // off-diagonal pairs count twice (Hermitian)
        }
        out[b * NQ + i] = r;
    }
}

extern "C" void kernel_launch(void* const* d_in, const int* in_sizes, int n_in,
                              void* d_out, int out_size, void* d_ws, size_t ws_size,
                              hipStream_t stream) {
    const float* z      = (const float*)d_in[0];
    const float* params = (const float*)d_in[1];
    const float* ew     = (const float*)d_in[2];
    float* out          = (float*)d_out;
    const int B = in_sizes[0] / NQ;
    qsim_kernel<<<B, 256, 0, stream>>>(z, params, ew, out);
}

// Round 2
// 64.982 us; speedup vs baseline: 1.1266x; 1.1266x over previous
//
#include <hip/hip_runtime.h>

#define NQ 16

// mag * (-i)^k
__device__ __forceinline__ float2 phase_val(float mag, int k) {
    switch (k & 3) {
        case 0:  return make_float2(mag, 0.f);
        case 1:  return make_float2(0.f, -mag);
        case 2:  return make_float2(-mag, 0.f);
        default: return make_float2(0.f, mag);
    }
}

// c*v0 - i*s*v1   (RX butterfly contribution)
__device__ __forceinline__ float2 rxmix(float2 v0, float2 v1, float c, float s) {
    return make_float2(c * v0.x + s * v1.y, c * v0.y - s * v1.x);
}

// One block per sample, 256 threads (4 waves).
//
// state = C2 R2 C1 R1 |0>;  RX angles merge (R1 absorbs layer-0), ring CNOTs are
// basis permutations, C2 is absorbed into the measurement (nested Z-string masks).
// C1 chi is rank-4 across the hi(0..7)/lo(8..15) cut:
//   X_{2a+t}(h) = A_t(h) [h&1==a],  Y_{2a+b}(l) = B_a(l) [l&1==b].
// R2 = (wires0..6)(wire7) x (wires8..14)(wire15); wires 0..6/8..14 act on bits 7..1
// and commute with the bit-0 projector, so we rotate only 4 arrays (A0,A1,B0,B1)
// and apply wires 7/15 as scalar 2x2 factors in the product phase.
// Gram sums G[side][m][pp] = sum_e sgn_m(e) u_p(e) conj(u_q(e)) are computed via a
// 64-point Walsh-Hadamard over lane bits (shfl_xor butterflies) + 4-wave combine.
extern "C" __global__ __launch_bounds__(256)
void qsim_kernel(const float* __restrict__ z,
                 const float* __restrict__ params,
                 const float* __restrict__ ew,
                 float* __restrict__ out)
{
    const int b    = blockIdx.x;
    const int tid  = threadIdx.x;
    const int lane = tid & 63;
    const int wv   = tid >> 6;        // wave id = array id (0:A0 1:A1 2:B0 3:B1)

    __shared__ float c1[NQ], s1[NQ], cw[NQ], sw[NQ];
    __shared__ __align__(16) float2 V4[4][258];     // rotated arrays, padded rows
    __shared__ __align__(16) float  PART[4][7][32]; // [wave][low-mask idx][array]
    __shared__ float2 G[2][9][10];

    if (tid < NQ) {
        float phi = z[b * NQ + tid] + params[tid] + ew[tid];  // embed + layer0 merged
        c1[tid] = cosf(0.5f * phi);
        s1[tid] = sinf(0.5f * phi);
        float w = 0.5f * ew[NQ + tid];                         // layer1 RX
        cw[tid] = cosf(w);
        sw[tid] = sinf(w);
    }
    __syncthreads();

    const bool hiw = (wv < 2);
    const int  par = wv & 1;          // t (hi) or a (lo) parameter of my array

    // ---- Step 2: build my array's 4 elements e = (k<<6)|lane ----
    float2 v[4];
#pragma unroll
    for (int k = 0; k < 4; ++k) {
        int e = (k << 6) | lane;
        float mag = 1.f; int kk = 0;
        if (hiw) {
            int y0 = (e >> 7) & 1;
            int eb = y0 ^ par;                 mag *= eb ? s1[0] : c1[0]; kk += eb;
            int y1 = (e >> 6) & 1;
            eb = y1 ^ y0 ^ par;                mag *= eb ? s1[1] : c1[1]; kk += eb;
            int yp = y1;
#pragma unroll
            for (int q = 2; q < 8; ++q) {
                int yq = (e >> (7 - q)) & 1;
                eb = yp ^ yq;                  mag *= eb ? s1[q] : c1[q]; kk += eb;
                yp = yq;
            }
        } else {
            int yp = (e >> 7) & 1;             // y8
            int eb = par ^ yp;                 mag *= eb ? s1[8] : c1[8]; kk += eb;
#pragma unroll
            for (int q = 9; q < 16; ++q) {
                int yq = (e >> (15 - q)) & 1;
                eb = yp ^ yq;                  mag *= eb ? s1[q] : c1[q]; kk += eb;
                yp = yq;
            }
        }
        v[k] = phase_val(mag, kk);
    }

    // ---- Step 3: rotate through 7 wires (bits 7..1). Wave-uniform angles. ----
    const int wb = hiw ? 0 : 8;
    {   // bit 7 (wire wb+0): pairs (0,2),(1,3)
        float c = cw[wb + 0], s = sw[wb + 0];
        float2 n0 = rxmix(v[0], v[2], c, s), n2 = rxmix(v[2], v[0], c, s);
        float2 n1 = rxmix(v[1], v[3], c, s), n3 = rxmix(v[3], v[1], c, s);
        v[0] = n0; v[1] = n1; v[2] = n2; v[3] = n3;
    }
    {   // bit 6 (wire wb+1): pairs (0,1),(2,3)
        float c = cw[wb + 1], s = sw[wb + 1];
        float2 n0 = rxmix(v[0], v[1], c, s), n1 = rxmix(v[1], v[0], c, s);
        float2 n2 = rxmix(v[2], v[3], c, s), n3 = rxmix(v[3], v[2], c, s);
        v[0] = n0; v[1] = n1; v[2] = n2; v[3] = n3;
    }
#pragma unroll
    for (int bbit = 5; bbit >= 1; --bbit) {   // wires wb+2..wb+6
        float c = cw[wb + 7 - bbit], s = sw[wb + 7 - bbit];
        int m = 1 << bbit;
#pragma unroll
        for (int k = 0; k < 4; ++k) {
            float px = __shfl_xor(v[k].x, m);
            float py = __shfl_xor(v[k].y, m);
            v[k] = make_float2(c * v[k].x + s * py, c * v[k].y - s * px);
        }
    }
#pragma unroll
    for (int k = 0; k < 4; ++k) V4[wv][(k << 6) | lane] = v[k];
    __syncthreads();

    // ---- Step 4a: per-element sector values + pair products ----
    const int e0 = tid & 1, j2 = tid & ~1;
    float4 rA0 = *(const float4*)&V4[0][j2];   // (alpha0, beta0)
    float4 rA1 = *(const float4*)&V4[1][j2];   // (alpha1, beta1)
    float4 rB0 = *(const float4*)&V4[2][j2];   // (gamma0, delta0)
    float4 rB1 = *(const float4*)&V4[3][j2];   // (gamma1, delta1)
    float c7 = cw[7], s7 = sw[7], c15 = cw[15], s15 = sw[15];

    float2 x[4], yv[4];
    {
        float2 a0 = make_float2(rA0.x, rA0.y), b0 = make_float2(rA0.z, rA0.w);
        float2 a1 = make_float2(rA1.x, rA1.y), b1 = make_float2(rA1.z, rA1.w);
        if (e0 == 0) {  // x[2a+t]: a=0 -> c7*alpha_t ; a=1 -> -i s7 * beta_t
            x[0] = make_float2(c7 * a0.x, c7 * a0.y);
            x[1] = make_float2(c7 * a1.x, c7 * a1.y);
            x[2] = make_float2(s7 * b0.y, -s7 * b0.x);
            x[3] = make_float2(s7 * b1.y, -s7 * b1.x);
        } else {
            x[0] = make_float2(s7 * a0.y, -s7 * a0.x);
            x[1] = make_float2(s7 * a1.y, -s7 * a1.x);
            x[2] = make_float2(c7 * b0.x, c7 * b0.y);
            x[3] = make_float2(c7 * b1.x, c7 * b1.y);
        }
        float2 g0 = make_float2(rB0.x, rB0.y), d0 = make_float2(rB0.z, rB0.w);
        float2 g1 = make_float2(rB1.x, rB1.y), d1 = make_float2(rB1.z, rB1.w);
        if (e0 == 0) {  // y[2a+b]: b=0 -> c15*gamma_a ; b=1 -> -i s15 * delta_a
            yv[0] = make_float2(c15 * g0.x, c15 * g0.y);
            yv[2] = make_float2(c15 * g1.x, c15 * g1.y);
            yv[1] = make_float2(s15 * d0.y, -s15 * d0.x);
            yv[3] = make_float2(s15 * d1.y, -s15 * d1.x);
        } else {
            yv[0] = make_float2(s15 * g0.y, -s15 * g0.x);
            yv[2] = make_float2(s15 * g1.y, -s15 * g1.x);
            yv[1] = make_float2(c15 * d0.x, c15 * d0.y);
            yv[3] = make_float2(c15 * d1.x, c15 * d1.y);
        }
    }

    float wr[32];
    {
        float2 *p = x;
#pragma unroll
        for (int side = 0; side < 2; ++side, p = yv) {
            int o = side * 16;
            wr[o + 0] = p[0].x * p[0].x + p[0].y * p[0].y;
            wr[o + 1] = p[1].x * p[1].x + p[1].y * p[1].y;
            wr[o + 2] = p[2].x * p[2].x + p[2].y * p[2].y;
            wr[o + 3] = p[3].x * p[3].x + p[3].y * p[3].y;
            wr[o + 4]  = p[0].x * p[1].x + p[0].y * p[1].y;
            wr[o + 5]  = p[0].y * p[1].x - p[0].x * p[1].y;
            wr[o + 6]  = p[0].x * p[2].x + p[0].y * p[2].y;
            wr[o + 7]  = p[0].y * p[2].x - p[0].x * p[2].y;
            wr[o + 8]  = p[0].x * p[3].x + p[0].y * p[3].y;
            wr[o + 9]  = p[0].y * p[3].x - p[0].x * p[3].y;
            wr[o + 10] = p[1].x * p[2].x + p[1].y * p[2].y;
            wr[o + 11] = p[1].y * p[2].x - p[1].x * p[2].y;
            wr[o + 12] = p[1].x * p[3].x + p[1].y * p[3].y;
            wr[o + 13] = p[1].y * p[3].x - p[1].x * p[3].y;
            wr[o + 14] = p[2].x * p[3].x + p[2].y * p[3].y;
            wr[o + 15] = p[2].y * p[3].x - p[2].x * p[3].y;
        }
    }

    // ---- Step 4b: 64-point WHT over lane bits: lane L ends with signed sum
    //      sum_l (-1)^popc(L&l) wr(l) for every array ----
#pragma unroll
    for (int lev = 0; lev < 6; ++lev) {
        int m = 1 << lev;
        float s = (lane & m) ? -1.f : 1.f;
#pragma unroll
        for (int a = 0; a < 32; ++a) {
            float wp = __shfl_xor(wr[a], m);
            wr[a] = fmaf(s, wr[a], wp);
        }
    }
    {   // needed low-6 sign patterns: top-down prefixes of bits 5..0
        int li = -1;
        switch (lane) {
            case 0x00: li = 0; break; case 0x20: li = 1; break;
            case 0x30: li = 2; break; case 0x38: li = 3; break;
            case 0x3C: li = 4; break; case 0x3E: li = 5; break;
            case 0x3F: li = 6; break;
        }
        if (li >= 0) {
#pragma unroll
            for (int a = 0; a < 32; ++a) PART[wv][li][a] = wr[a];
        }
    }
    __syncthreads();

    // ---- Step 4c: combine waves (bits 6,7) into G[side][m][pp] ----
    if (tid < 180) {
        int side = tid / 90, rest = tid - side * 90;
        int pp = rest / 9, m = rest - pp * 9;
        int M;
        if (side == 0) M = (m < 8) ? (((1 << (m + 1)) - 1) << (7 - m)) : 0x7F;
        else           M = (m == 0) ? 0 : (((1 << m) - 1) << (8 - m));
        int low = M & 63, hi2 = M >> 6;
        int li2 = 0;
        switch (low) {
            case 0x00: li2 = 0; break; case 0x20: li2 = 1; break;
            case 0x30: li2 = 2; break; case 0x38: li2 = 3; break;
            case 0x3C: li2 = 4; break; case 0x3E: li2 = 5; break;
            default:   li2 = 6; break;  // 0x3F
        }
        int rs; bool diag;
        switch (pp) {
            case 0: rs = 0;  diag = true;  break;
            case 1: rs = 4;  diag = false; break;
            case 2: rs = 6;  diag = false; break;
            case 3: rs = 8;  diag = false; break;
            case 4: rs = 1;  diag = true;  break;
            case 5: rs = 10; diag = false; break;
            case 6: rs = 12; diag = false; break;
            case 7: rs = 2;  diag = true;  break;
            case 8: rs = 14; diag = false; break;
            default: rs = 3; diag = true;  break;
        }
        float gr = 0.f, gi = 0.f;
#pragma unroll
        for (int w2 = 0; w2 < 4; ++w2) {
            float s = (__popc(hi2 & w2) & 1) ? -1.f : 1.f;
            gr = fmaf(s, PART[w2][li2][side * 16 + rs], gr);
            if (!diag) gi = fmaf(s, PART[w2][li2][side * 16 + rs + 1], gi);
        }
        G[side][m][pp] = make_float2(gr, gi);
    }
    __syncthreads();

    // ---- Step 5: out[i] = sum_pp w_pp * Re(Gh * Gl) ----
    if (tid < NQ) {
        const int i = tid;
        int hm, lm;
        if (i == 0)      { hm = 8; lm = 8; }     // Z-string {1..15}
        else if (i <= 7) { hm = i; lm = 0; }     // {0..i}
        else             { hm = 7; lm = i - 7; } // {0..i}
        float r = 0.f;
#pragma unroll
        for (int pp = 0; pp < 10; ++pp) {
            float2 gh = G[0][hm][pp];
            float2 gl = G[1][lm][pp];
            float re = gh.x * gl.x - gh.y * gl.y;
            bool diag = (pp == 0) || (pp == 4) || (pp == 7) || (pp == 9);
            r += (diag ? 1.f : 2.f) * re;
        }
        out[b * NQ + i] = r;
    }
}

extern "C" void kernel_launch(void* const* d_in, const int* in_sizes, int n_in,
                              void* d_out, int out_size, void* d_ws, size_t ws_size,
                              hipStream_t stream) {
    const float* z      = (const float*)d_in[0];
    const float* params = (const float*)d_in[1];
    const float* ew     = (const float*)d_in[2];
    float* out          = (float*)d_out;
    const int B = in_sizes[0] / NQ;
    qsim_kernel<<<B, 256, 0, stream>>>(z, params, ew, out);
}